// Round 6
// baseline (484.728 us; speedup 1.0000x reference)
//
#include <hip/hip_runtime.h>

#define CRF_B 1024
#define CRF_T 512
#define CRF_K 64
#define CRF_START 62
#define CRF_STOP 63

typedef float vf16 __attribute__((ext_vector_type(16)));

__device__ __forceinline__ float bcastf(float v, int lane) {
  return __int_as_float(__builtin_amdgcn_readlane(__float_as_int(v), lane));
}

__device__ __forceinline__ float wave_sum64(float v) {
#pragma unroll
  for (int off = 32; off > 0; off >>= 1) v += __shfl_xor(v, off, 64);
  return v;
}

// R4 (fourth resubmit, unmeasured due to GPU acquisition timeouts):
// symmetric waves. R3 post-mortem: after gold waves retired, only 2/4 SIMDs
// per CU held a forward wave (VALUBusy 18.6%; instr-count cross-check shows
// readlane is full-rate and the kernel is stall/parallelism-bound). Now every
// wave = {gold for its 2 batches, then 2-chain interleaved forward}:
// grid 256 blocks x 2 waves -> 4 forward waves/CU, one per SIMD, no idle roles.
__global__ __launch_bounds__(128, 1) void crf_kernel(
    const float* __restrict__ feats, const int* __restrict__ lengths,
    const int* __restrict__ tags, const float* __restrict__ trans,
    float* __restrict__ out) {
  __shared__ float sT[CRF_K * 65];  // padded stride 65: conflict-free

  const int tid = threadIdx.x;
  const int lane = tid & 63;
  const int wv = tid >> 6;               // 0 or 1
  const int bA = 4 * blockIdx.x + 2 * wv;
  const int bB = bA + 1;

  for (int idx = tid; idx < CRF_K * CRF_K; idx += 128)
    sT[(idx >> 6) * 65 + (idx & 63)] = trans[idx];
  __syncthreads();

  const int La = lengths[bA];
  const int Lb = lengths[bB];

  // ---------------- gold scores for both batches (parallel, ~us) ----------
  float goldsum = 0.0f;
#pragma unroll
  for (int bi = 0; bi < 2; ++bi) {
    const int bb = bA + bi;
    const int L = bi ? Lb : La;
    const int* btags = tags + bb * CRF_T;
    const float* bf = feats + (size_t)bb * CRF_T * CRF_K;
    float g = 0.0f;
#pragma unroll
    for (int base = 0; base < CRF_T; base += 64) {
      int t = base + lane;
      if (t < L) {
        int tg = btags[t];
        int tp = (t == 0) ? CRF_START : btags[t - 1];
        g += bf[(size_t)t * CRF_K + tg];  // emit score
        g += sT[tg * 65 + tp];            // transition score
      }
    }
    g = wave_sum64(g);                       // same value in all lanes
    g += sT[CRF_STOP * 65 + btags[L - 1]];   // terminal transition (broadcast)
    goldsum += g;
  }

  // ---------------- forward recurrence, 2 chains, exp domain --------------
  // lane i holds E row i = exp(trans[i][0..63]) in four ext-vector SSA
  // values (VGPR-resident: no alloca, constant-index extracts only).
  vf16 E0, E1, E2, E3;
  {
    const float* trow = &sT[lane * 65];
#pragma unroll
    for (int j = 0; j < 16; ++j) E0[j] = __expf(trow[j]);
#pragma unroll
    for (int j = 0; j < 16; ++j) E1[j] = __expf(trow[16 + j]);
#pragma unroll
    for (int j = 0; j < 16; ++j) E2[j] = __expf(trow[32 + j]);
#pragma unroll
    for (int j = 0; j < 16; ++j) E3[j] = __expf(trow[48 + j]);
  }

  const float* fbA = feats + (size_t)bA * CRF_T * CRF_K + lane;
  const float* fbB = feats + (size_t)bB * CRF_T * CRF_K + lane;

  float PA = (lane == CRF_START) ? 1.0f : 0.0f;
  float PB = PA;
  float offA = 0.0f, offB = 0.0f;

  float eA[8], eB[8], fA[8], fB[8];
#pragma unroll
  for (int r = 0; r < 8; ++r) eA[r] = fbA[r * CRF_K];
#pragma unroll
  for (int r = 0; r < 8; ++r) eB[r] = fbB[r * CRF_K];

  // one step, one chain: P' = (E . P) * exp(emit); col STOP of E is 0 -> skip j=63
  auto stepA = [&](float ee) {
    float a0 = 0.f, a1 = 0.f, a2 = 0.f, a3 = 0.f;
#pragma unroll
    for (int j = 0; j < 16; ++j) a0 = __builtin_fmaf(E0[j], bcastf(PA, j), a0);
#pragma unroll
    for (int j = 0; j < 16; ++j) a1 = __builtin_fmaf(E1[j], bcastf(PA, 16 + j), a1);
#pragma unroll
    for (int j = 0; j < 16; ++j) a2 = __builtin_fmaf(E2[j], bcastf(PA, 32 + j), a2);
#pragma unroll
    for (int j = 0; j < 15; ++j) a3 = __builtin_fmaf(E3[j], bcastf(PA, 48 + j), a3);
    PA = ((a0 + a1) + (a2 + a3)) * ee;
  };
  auto stepB = [&](float ee) {
    float b0 = 0.f, b1 = 0.f, b2 = 0.f, b3 = 0.f;
#pragma unroll
    for (int j = 0; j < 16; ++j) b0 = __builtin_fmaf(E0[j], bcastf(PB, j), b0);
#pragma unroll
    for (int j = 0; j < 16; ++j) b1 = __builtin_fmaf(E1[j], bcastf(PB, 16 + j), b1);
#pragma unroll
    for (int j = 0; j < 16; ++j) b2 = __builtin_fmaf(E2[j], bcastf(PB, 32 + j), b2);
#pragma unroll
    for (int j = 0; j < 15; ++j) b3 = __builtin_fmaf(E3[j], bcastf(PB, 48 + j), b3);
    PB = ((b0 + b1) + (b2 + b3)) * ee;
  };
  // fused step: 8 independent FMA chains + 2 independent readlane streams
  // (fills the readlane->SGPR->FMA hazard slots).
  auto step2 = [&](float ea, float eb) {
    float a0 = 0.f, a1 = 0.f, a2 = 0.f, a3 = 0.f;
    float b0 = 0.f, b1 = 0.f, b2 = 0.f, b3 = 0.f;
#pragma unroll
    for (int j = 0; j < 16; ++j) {
      a0 = __builtin_fmaf(E0[j], bcastf(PA, j), a0);
      b0 = __builtin_fmaf(E0[j], bcastf(PB, j), b0);
    }
#pragma unroll
    for (int j = 0; j < 16; ++j) {
      a1 = __builtin_fmaf(E1[j], bcastf(PA, 16 + j), a1);
      b1 = __builtin_fmaf(E1[j], bcastf(PB, 16 + j), b1);
    }
#pragma unroll
    for (int j = 0; j < 16; ++j) {
      a2 = __builtin_fmaf(E2[j], bcastf(PA, 32 + j), a2);
      b2 = __builtin_fmaf(E2[j], bcastf(PB, 32 + j), b2);
    }
#pragma unroll
    for (int j = 0; j < 15; ++j) {
      a3 = __builtin_fmaf(E3[j], bcastf(PA, 48 + j), a3);
      b3 = __builtin_fmaf(E3[j], bcastf(PB, 48 + j), b3);
    }
    PA = ((a0 + a1) + (a2 + a3)) * ea;
    PB = ((b0 + b1) + (b2 + b3)) * eb;
  };

  // wave-uniform rescale by lane 0's P (LSE identity holds for ANY finite
  // normalizer; P[0] > 0 after step 1). One readlane, no max butterfly.
  auto rescaleA = [&](bool first) {
    float M = first ? 1.0f : bcastf(PA, 0);
    offA += __logf(M);
    PA *= __builtin_amdgcn_rcpf(M);
  };
  auto rescaleB = [&](bool first) {
    float M = first ? 1.0f : bcastf(PB, 0);
    offB += __logf(M);
    PB *= __builtin_amdgcn_rcpf(M);
  };

  const int Lmax = (La > Lb) ? La : Lb;
  for (int t0 = 0; t0 < Lmax; t0 += 8) {
    const int tn = t0 + 8;
    int nA = La - t0; nA = (nA < 0) ? 0 : ((nA > 8) ? 8 : nA);
    int nB = Lb - t0; nB = (nB < 0) ? 0 : ((nB > 8) ? 8 : nB);

    // prefetch next 8-step block per chain (wave-uniform branches)
    if (tn < La) {
#pragma unroll
      for (int r = 0; r < 8; ++r) fA[r] = fbA[(tn + r) * CRF_K];
    } else {
#pragma unroll
      for (int r = 0; r < 8; ++r) fA[r] = 0.0f;
    }
    if (tn < Lb) {
#pragma unroll
      for (int r = 0; r < 8; ++r) fB[r] = fbB[(tn + r) * CRF_K];
    } else {
#pragma unroll
      for (int r = 0; r < 8; ++r) fB[r] = 0.0f;
    }

    float eeA[8], eeB[8];
#pragma unroll
    for (int r = 0; r < 8; ++r) eeA[r] = __expf(eA[r]);  // off-chain, hides
#pragma unroll
    for (int r = 0; r < 8; ++r) eeB[r] = __expf(eB[r]);

    if (nA > 0) rescaleA(t0 == 0);  // growth over 8 steps ~e^64 < f32 max
    if (nB > 0) rescaleB(t0 == 0);

    if (nA == 8 && nB == 8) {
#pragma unroll
      for (int r = 0; r < 8; ++r) step2(eeA[r], eeB[r]);
    } else if (nA == 8 && nB == 0) {
#pragma unroll
      for (int r = 0; r < 8; ++r) stepA(eeA[r]);
    } else if (nB == 8 && nA == 0) {
#pragma unroll
      for (int r = 0; r < 8; ++r) stepB(eeB[r]);
    } else {  // partial block: happens at most twice per wave
#pragma unroll
      for (int r = 0; r < 8; ++r) {
        if (r < nA) stepA(eeA[r]);
        if (r < nB) stepB(eeB[r]);
      }
    }

#pragma unroll
    for (int r = 0; r < 8; ++r) eA[r] = fA[r];
#pragma unroll
    for (int r = 0; r < 8; ++r) eB[r] = fB[r];
  }

  // terminal: fwd = offset + log( sum_i P[i] * exp(trans[STOP][i]) )
  float eST = __expf(sT[CRF_STOP * 65 + lane]);  // exp(-10000)=0 kills i=STOP
  float sA = wave_sum64(PA * eST);
  float sB = wave_sum64(PB * eST);
  if (lane == 0) {
    float fwd = (offA + __logf(sA)) + (offB + __logf(sB));
    atomicAdd(out, (fwd - goldsum) * (1.0f / CRF_B));
  }
}

extern "C" void kernel_launch(void* const* d_in, const int* in_sizes, int n_in,
                              void* d_out, int out_size, void* d_ws, size_t ws_size,
                              hipStream_t stream) {
  const float* feats = (const float*)d_in[0];
  const int* lengths = (const int*)d_in[1];
  const int* tags = (const int*)d_in[2];
  const float* trans = (const float*)d_in[3];
  float* out = (float*)d_out;
  hipMemsetAsync(out, 0, sizeof(float), stream);
  crf_kernel<<<CRF_B / 4, 128, 0, stream>>>(feats, lengths, tags, trans, out);
}

// Round 7
// 300.552 us; speedup vs baseline: 1.6128x; 1.6128x over previous
//
#include <hip/hip_runtime.h>

#define CRF_B 1024
#define CRF_T 512
#define CRF_K 64
#define CRF_START 62
#define CRF_STOP 63

typedef float vf16 __attribute__((ext_vector_type(16)));

__device__ __forceinline__ float bcastf(float v, int lane) {
  return __int_as_float(__builtin_amdgcn_readlane(__float_as_int(v), lane));
}

__device__ __forceinline__ float wave_sum64(float v) {
#pragma unroll
  for (int off = 32; off > 0; off >>= 1) v += __shfl_xor(v, off, 64);
  return v;
}

// R5: REVERT to R0 structure (harness 299.7us; best measured). R3 (2-chain,
// 512 blocks, 390us) and R4 (symmetric waves, 485us) both REGRESSED: dispatch
// is a latency race on the longest chain (L=512), and bundling 2 chains per
// wave doubles the critical wave's per-step work (1148cy/step-pair vs 727cy
// solo). The one transferable R3 finding: interleaving independent readlanes
// between dependent readlane->FMA pairs cuts per-chain latency 727->574cy.
// R5 = R0 + that fix only: batch 8 readlanes, then 8 FMAs into 8 independent
// accumulators (issue floor 252cy/step; predict ~350-450cy vs R0's 727).
__global__ __launch_bounds__(128, 1) void crf_kernel(
    const float* __restrict__ feats, const int* __restrict__ lengths,
    const int* __restrict__ tags, const float* __restrict__ trans,
    float* __restrict__ out) {
  // padded stride 65: conflict-free row reads, cheap random reads for gold wave
  __shared__ float sT[CRF_K * 65];

  const int b = blockIdx.x;
  const int tid = threadIdx.x;
  const int lane = tid & 63;

  for (int idx = tid; idx < CRF_K * CRF_K; idx += 128)
    sT[(idx >> 6) * 65 + (idx & 63)] = trans[idx];
  __syncthreads();

  const int L = lengths[b];

  if (tid < 64) {
    // ---------------- forward wave (exp domain) ----------------
    // lane i holds E row i = exp(trans[i][0..63]) in four ext-vector SSA
    // values (VGPR-resident: no alloca, constant-index extracts only).
    vf16 E0, E1, E2, E3;
    {
      const float* trow = &sT[lane * 65];
#pragma unroll
      for (int j = 0; j < 16; ++j) E0[j] = __expf(trow[j]);
#pragma unroll
      for (int j = 0; j < 16; ++j) E1[j] = __expf(trow[16 + j]);
#pragma unroll
      for (int j = 0; j < 16; ++j) E2[j] = __expf(trow[32 + j]);
#pragma unroll
      for (int j = 0; j < 16; ++j) E3[j] = __expf(trow[48 + j]);
    }

    const float* bfeats = feats + (size_t)b * CRF_T * CRF_K + lane;

    // P[i] = exp(alpha[i] - offset); alpha0 = delta_START
    float P = (lane == CRF_START) ? 1.0f : 0.0f;
    float offset = 0.0f;

    float e[8], f[8];
#pragma unroll
    for (int r = 0; r < 8; ++r) e[r] = bfeats[r * CRF_K];

    // constant-index E element access (folds after unroll)
    auto Eget = [&](int idx) -> float {
      return idx < 16 ? E0[idx]
           : idx < 32 ? E1[idx - 16]
           : idx < 48 ? E2[idx - 32]
                      : E3[idx - 48];
    };

    // one step: P' = (E . P) * exp(emit). Column STOP of E is exactly 0 ->
    // skip j=63. R5 change: 8 readlanes batched ahead of 8 FMAs (8 groups),
    // 8 independent accumulator chains -> dependent readlane->FMA pairs get
    // 7 independent readlanes between them (R3 evidence: this hides the
    // SGPR-read hazard; R0's adjacent pairs cost ~727cy/step vs 252 floor).
    auto do_step = [&](float ee) {
      float acc0 = 0.f, acc1 = 0.f, acc2 = 0.f, acc3 = 0.f;
      float acc4 = 0.f, acc5 = 0.f, acc6 = 0.f, acc7 = 0.f;
#pragma unroll
      for (int g = 0; g < 8; ++g) {
        float s0 = bcastf(P, g * 8 + 0);
        float s1 = bcastf(P, g * 8 + 1);
        float s2 = bcastf(P, g * 8 + 2);
        float s3 = bcastf(P, g * 8 + 3);
        float s4 = bcastf(P, g * 8 + 4);
        float s5 = bcastf(P, g * 8 + 5);
        float s6 = bcastf(P, g * 8 + 6);
        float s7 = (g == 7) ? 0.0f : bcastf(P, g * 8 + 7);  // col STOP == 0
        acc0 = __builtin_fmaf(Eget(g * 8 + 0), s0, acc0);
        acc1 = __builtin_fmaf(Eget(g * 8 + 1), s1, acc1);
        acc2 = __builtin_fmaf(Eget(g * 8 + 2), s2, acc2);
        acc3 = __builtin_fmaf(Eget(g * 8 + 3), s3, acc3);
        acc4 = __builtin_fmaf(Eget(g * 8 + 4), s4, acc4);
        acc5 = __builtin_fmaf(Eget(g * 8 + 5), s5, acc5);
        acc6 = __builtin_fmaf(Eget(g * 8 + 6), s6, acc6);
        if (g != 7) acc7 = __builtin_fmaf(Eget(g * 8 + 7), s7, acc7);
      }
      float r = ((acc0 + acc1) + (acc2 + acc3)) + ((acc4 + acc5) + (acc6 + acc7));
      P = r * ee;
    };

    // wave-uniform rescale by lane 0's P (LSE identity holds for ANY finite
    // normalizer; P[0] > 0 after step 1 since only row START of E is all-zero).
    auto rescale = [&](int first) {
      float M = first ? 1.0f : bcastf(P, 0);
      offset += __logf(M);
      P *= __builtin_amdgcn_rcpf(M);
    };

    const int Lb = L & ~7;
    for (int t0 = 0; t0 < Lb; t0 += 8) {
      const int tn = t0 + 8;
      if (tn < CRF_T) {  // prefetch next 8-step block (wave-uniform branch)
#pragma unroll
        for (int r = 0; r < 8; ++r) f[r] = bfeats[(tn + r) * CRF_K];
      } else {
#pragma unroll
        for (int r = 0; r < 8; ++r) f[r] = 0.0f;
      }
      float ee[8];
#pragma unroll
      for (int r = 0; r < 8; ++r) ee[r] = __expf(e[r]);  // off-chain, hides

      rescale(t0 == 0);  // growth over 8 steps ~e^64 < f32 max (R2 verified)

#pragma unroll
      for (int r = 0; r < 8; ++r) do_step(ee[r]);
#pragma unroll
      for (int r = 0; r < 8; ++r) e[r] = f[r];
    }

    // tail (<= 7 steps)
    if (Lb < L) {
      rescale(Lb == 0);
#pragma unroll
      for (int r = 0; r < 8; ++r) {
        if (Lb + r < L) do_step(__expf(e[r]));
      }
    }

    // terminal: fwd = offset + log( sum_i P[i] * exp(trans[STOP][i]) )
    float eST = __expf(sT[CRF_STOP * 65 + lane]);  // exp(-10000)=0 kills i=STOP
    float v = P * eST;
    float s2 = wave_sum64(v);
    float fwd = offset + __logf(s2);
    if (lane == 0) atomicAdd(out, fwd * (1.0f / CRF_B));
  } else {
    // ---------------- gold wave (fully parallel) ----------------
    const int* btags = tags + b * CRF_T;
    const float* bf = feats + (size_t)b * CRF_T * CRF_K;
    float gold = 0.0f;
#pragma unroll
    for (int base = 0; base < CRF_T; base += 64) {
      int t = base + lane;
      if (t < L) {
        int tg = btags[t];
        int tp = (t == 0) ? CRF_START : btags[t - 1];
        gold += bf[(size_t)t * CRF_K + tg];   // emit score
        gold += sT[tg * 65 + tp];             // transition score
      }
    }
    gold = wave_sum64(gold);
    if (lane == 0) {
      gold += sT[CRF_STOP * 65 + btags[L - 1]];  // terminal transition
      atomicAdd(out, -gold * (1.0f / CRF_B));
    }
  }
}

extern "C" void kernel_launch(void* const* d_in, const int* in_sizes, int n_in,
                              void* d_out, int out_size, void* d_ws, size_t ws_size,
                              hipStream_t stream) {
  const float* feats = (const float*)d_in[0];
  const int* lengths = (const int*)d_in[1];
  const int* tags = (const int*)d_in[2];
  const float* trans = (const float*)d_in[3];
  float* out = (float*)d_out;
  hipMemsetAsync(out, 0, sizeof(float), stream);
  crf_kernel<<<CRF_B, 128, 0, stream>>>(feats, lengths, tags, trans, out);
}